// Round 2
// baseline (1751.299 us; speedup 1.0000x reference)
//
#include <hip/hip_runtime.h>

// Problem constants (from setup_inputs)
#define N_NODES 20000
#define NANG 8
#define CH 64                      // in_size == out_size == 64
#define M_ROWS (NANG * N_NODES)    // 160000
#define E_EDGES (M_ROWS * 16)      // 2560000
#define K_CHEB 8
#define WK_STRIDE (NANG * CH * CH) // 32768 floats per weight[k]

// ---------------- CSR build ----------------

__global__ void hist_kernel(const int* __restrict__ rows, int* __restrict__ counts) {
    int e = blockIdx.x * 256 + threadIdx.x;
    if (e < E_EDGES) atomicAdd(&counts[rows[e]], 1);
}

__global__ void scan1_kernel(const int* __restrict__ counts, int* __restrict__ excl,
                             int* __restrict__ bsum) {
    __shared__ int s[1024];
    int i = blockIdx.x * 1024 + threadIdx.x;
    int v = (i < M_ROWS) ? counts[i] : 0;
    s[threadIdx.x] = v;
    __syncthreads();
    for (int off = 1; off < 1024; off <<= 1) {
        int t = (threadIdx.x >= off) ? s[threadIdx.x - off] : 0;
        __syncthreads();
        s[threadIdx.x] += t;
        __syncthreads();
    }
    if (i < M_ROWS) excl[i] = s[threadIdx.x] - v;
    if (threadIdx.x == 1023) bsum[blockIdx.x] = s[1023];
}

__global__ void scan2_kernel(int* bsum, int nb) {
    __shared__ int s[256];
    int v = (threadIdx.x < nb) ? bsum[threadIdx.x] : 0;
    s[threadIdx.x] = v;
    __syncthreads();
    for (int off = 1; off < 256; off <<= 1) {
        int t = (threadIdx.x >= off) ? s[threadIdx.x - off] : 0;
        __syncthreads();
        s[threadIdx.x] += t;
        __syncthreads();
    }
    if (threadIdx.x < nb) bsum[threadIdx.x] = s[threadIdx.x] - v;  // exclusive
    if (threadIdx.x == 255) bsum[nb] = s[255];                     // total
}

__global__ void scan3_kernel(int* __restrict__ row_start, const int* __restrict__ bsum, int nb) {
    int i = blockIdx.x * 1024 + threadIdx.x;
    if (i < M_ROWS) row_start[i] += bsum[i >> 10];
    else if (i == M_ROWS) row_start[M_ROWS] = bsum[nb];
}

__global__ void scatter_kernel(const int* __restrict__ rows, const int* __restrict__ cols,
                               const float* __restrict__ vals,
                               const int* __restrict__ row_start, int* __restrict__ fill,
                               int2* __restrict__ edges) {
    int e = blockIdx.x * 256 + threadIdx.x;
    if (e >= E_EDGES) return;
    int r = rows[e];
    int p = atomicAdd(&fill[r], 1);
    edges[row_start[r] + p] = make_int2(cols[e], __float_as_int(vals[e]));
}

// ---------------- T0 = tile(x) ----------------

__global__ void tile_kernel(const float* __restrict__ x, float* __restrict__ T0) {
    int idx = blockIdx.x * 256 + threadIdx.x;       // covers N_NODES*CH
    T0[(size_t)blockIdx.y * (N_NODES * CH) + idx] = x[idx];
}

// ---------------- SpMM: Tout = alpha * (L @ Tin) + beta * Tsub ----------------
// one wave per row; lane = channel. Gathers are 256B coalesced per edge.

__global__ __launch_bounds__(256) void spmm_kernel(
        const int* __restrict__ row_start, const int2* __restrict__ edges,
        const float* __restrict__ Tin, const float* __restrict__ Tsub,
        float* __restrict__ Tout, float alpha, float beta) {
    int r = (blockIdx.x * 256 + threadIdx.x) >> 6;
    int lane = threadIdx.x & 63;
    if (r >= M_ROWS) return;
    int s = row_start[r];
    int e = row_start[r + 1];
    float acc = 0.f;
    int j = s;
    // unroll-by-2 to get two independent gathers in flight
    for (; j + 1 < e; j += 2) {
        int2 e0 = edges[j];
        int2 e1 = edges[j + 1];
        float t0 = Tin[(size_t)e0.x * CH + lane];
        float t1 = Tin[(size_t)e1.x * CH + lane];
        acc = fmaf(__int_as_float(e0.y), t0, acc);
        acc = fmaf(__int_as_float(e1.y), t1, acc);
    }
    if (j < e) {
        int2 e0 = edges[j];
        acc = fmaf(__int_as_float(e0.y), Tin[(size_t)e0.x * CH + lane], acc);
    }
    size_t oi = (size_t)r * CH + lane;
    Tout[oi] = alpha * acc + beta * Tsub[oi];
}

// ---------------- GEMM: out (+)= feat(T) @ Wk (+ bias) ----------------
// block: 32 nodes x 64 outputs, 256 threads (o = tid&63, iq = tid>>6),
// 8 nodes per thread. W tile and transposed T tile staged in LDS.

template <int ACC>
__global__ __launch_bounds__(256) void gemm_kernel(
        const float* __restrict__ T,      // [NANG*N_NODES, 64]
        const float* __restrict__ W,      // [NANG*64, 64] (this k)
        const float* __restrict__ bias,
        float* __restrict__ out) {        // [N_NODES, 64]
    __shared__ float Wl[64 * 64];
    __shared__ float Tl[64 * 36];         // transposed [c][i], i-stride 36 (16B aligned, conflict-free reads)
    int tid = threadIdx.x;
    int o = tid & 63;
    int iq = tid >> 6;                    // 0..3
    int n0 = blockIdx.x * 32;
    float acc[8];
#pragma unroll
    for (int j = 0; j < 8; ++j) acc[j] = 0.f;

    for (int a = 0; a < NANG; ++a) {
        __syncthreads();
#pragma unroll
        for (int t = 0; t < 16; ++t) {
            int idx = tid + t * 256;
            Wl[idx] = W[a * 4096 + idx];
        }
#pragma unroll
        for (int t = 0; t < 8; ++t) {
            int idx = tid + t * 256;      // 0..2047 = 32 nodes x 64 ch
            int i = idx >> 6, c = idx & 63;
            Tl[c * 36 + i] = T[((size_t)(a * N_NODES + n0 + i)) * CH + c];
        }
        __syncthreads();
#pragma unroll 4
        for (int c = 0; c < 64; ++c) {
            float w = Wl[c * 64 + o];
            const float4 t0 = *(const float4*)&Tl[c * 36 + iq * 8];
            const float4 t1 = *(const float4*)&Tl[c * 36 + iq * 8 + 4];
            acc[0] = fmaf(t0.x, w, acc[0]);
            acc[1] = fmaf(t0.y, w, acc[1]);
            acc[2] = fmaf(t0.z, w, acc[2]);
            acc[3] = fmaf(t0.w, w, acc[3]);
            acc[4] = fmaf(t1.x, w, acc[4]);
            acc[5] = fmaf(t1.y, w, acc[5]);
            acc[6] = fmaf(t1.z, w, acc[6]);
            acc[7] = fmaf(t1.w, w, acc[7]);
        }
    }
    float b = bias[o];
#pragma unroll
    for (int j = 0; j < 8; ++j) {
        size_t oi = (size_t)(n0 + iq * 8 + j) * CH + o;
        if (ACC) out[oi] += acc[j];
        else out[oi] = acc[j] + b;
    }
}

// ---------------- launch ----------------

extern "C" void kernel_launch(void* const* d_in, const int* in_sizes, int n_in,
                              void* d_out, int out_size, void* d_ws, size_t ws_size,
                              hipStream_t stream) {
    (void)in_sizes; (void)n_in; (void)out_size; (void)ws_size;
    const float* x       = (const float*)d_in[0];
    const float* ls_vals = (const float*)d_in[1];
    const float* weight  = (const float*)d_in[2];
    const float* bias    = (const float*)d_in[3];
    const int*   ls_rows = (const int*)d_in[4];
    const int*   ls_cols = (const int*)d_in[5];
    float* out = (float*)d_out;

    char* ws = (char*)d_ws;
    size_t off = 0;
    auto alloc = [&](size_t bytes) -> void* {
        void* p = ws + off;
        off += (bytes + 255) & ~(size_t)255;
        return p;
    };
    int*  row_start = (int*)alloc((M_ROWS + 1) * sizeof(int));
    int*  fill      = (int*)alloc(M_ROWS * sizeof(int));       // doubles as counts
    int*  bsum      = (int*)alloc(1024 * sizeof(int));
    int2* edges     = (int2*)alloc((size_t)E_EDGES * sizeof(int2));
    float* T0 = (float*)alloc((size_t)M_ROWS * CH * sizeof(float));
    float* T1 = (float*)alloc((size_t)M_ROWS * CH * sizeof(float));
    float* T2 = (float*)alloc((size_t)M_ROWS * CH * sizeof(float));

    const int nb = (M_ROWS + 1023) / 1024;   // 157

    // CSR build
    hipMemsetAsync(fill, 0, M_ROWS * sizeof(int), stream);
    hist_kernel<<<(E_EDGES + 255) / 256, 256, 0, stream>>>(ls_rows, fill);
    scan1_kernel<<<nb, 1024, 0, stream>>>(fill, row_start, bsum);
    scan2_kernel<<<1, 256, 0, stream>>>(bsum, nb);
    scan3_kernel<<<nb + 1, 1024, 0, stream>>>(row_start, bsum, nb);
    hipMemsetAsync(fill, 0, M_ROWS * sizeof(int), stream);
    scatter_kernel<<<(E_EDGES + 255) / 256, 256, 0, stream>>>(
        ls_rows, ls_cols, ls_vals, row_start, fill, edges);

    // Tx0 = tile(x); out = feat(Tx0) @ W0 + bias
    tile_kernel<<<dim3(N_NODES * CH / 256, NANG), 256, 0, stream>>>(x, T0);
    gemm_kernel<0><<<N_NODES / 32, 256, 0, stream>>>(T0, weight, bias, out);

    // Tx1 = L @ Tx0 ; out += feat(Tx1) @ W1
    spmm_kernel<<<M_ROWS / 4, 256, 0, stream>>>(row_start, edges, T0, T0, T1, 1.f, 0.f);
    gemm_kernel<1><<<N_NODES / 32, 256, 0, stream>>>(T1, weight + WK_STRIDE, bias, out);

    // Chebyshev: Tx2 = 2 L Tx1 - Tx0
    float* Tp = T0;
    float* Tc = T1;
    float* Tn = T2;
    for (int k = 2; k < K_CHEB; ++k) {
        spmm_kernel<<<M_ROWS / 4, 256, 0, stream>>>(row_start, edges, Tc, Tp, Tn, 2.f, -1.f);
        gemm_kernel<1><<<N_NODES / 32, 256, 0, stream>>>(Tn, weight + (size_t)k * WK_STRIDE, bias, out);
        float* t = Tp; Tp = Tc; Tc = Tn; Tn = t;
    }
}

// Round 3
// 1301.122 us; speedup vs baseline: 1.3460x; 1.3460x over previous
//
#include <hip/hip_runtime.h>
#include <hip/hip_bf16.h>

// Problem constants (from setup_inputs)
#define N_NODES 20000
#define NANG 8
#define CH 64                      // in_size == out_size == 64
#define M_ROWS (NANG * N_NODES)    // 160000
#define E_EDGES (M_ROWS * 16)      // 2560000
#define K_CHEB 8
#define WK_STRIDE (NANG * CH * CH) // 32768 floats per weight[k]

typedef short short8 __attribute__((ext_vector_type(8)));
typedef float f32x4 __attribute__((ext_vector_type(4)));

// ---------------- CSR build ----------------

__global__ void hist_kernel(const int* __restrict__ rows, int* __restrict__ counts) {
    int e = blockIdx.x * 256 + threadIdx.x;
    if (e < E_EDGES) atomicAdd(&counts[rows[e]], 1);
}

__global__ void scan1_kernel(const int* __restrict__ counts, int* __restrict__ excl,
                             int* __restrict__ bsum) {
    __shared__ int s[1024];
    int i = blockIdx.x * 1024 + threadIdx.x;
    int v = (i < M_ROWS) ? counts[i] : 0;
    s[threadIdx.x] = v;
    __syncthreads();
    for (int off = 1; off < 1024; off <<= 1) {
        int t = (threadIdx.x >= off) ? s[threadIdx.x - off] : 0;
        __syncthreads();
        s[threadIdx.x] += t;
        __syncthreads();
    }
    if (i < M_ROWS) excl[i] = s[threadIdx.x] - v;
    if (threadIdx.x == 1023) bsum[blockIdx.x] = s[1023];
}

__global__ void scan2_kernel(int* bsum, int nb) {
    __shared__ int s[256];
    int v = (threadIdx.x < nb) ? bsum[threadIdx.x] : 0;
    s[threadIdx.x] = v;
    __syncthreads();
    for (int off = 1; off < 256; off <<= 1) {
        int t = (threadIdx.x >= off) ? s[threadIdx.x - off] : 0;
        __syncthreads();
        s[threadIdx.x] += t;
        __syncthreads();
    }
    if (threadIdx.x < nb) bsum[threadIdx.x] = s[threadIdx.x] - v;  // exclusive
    if (threadIdx.x == 255) bsum[nb] = s[255];                     // total
}

__global__ void scan3_kernel(int* __restrict__ row_start, const int* __restrict__ bsum, int nb) {
    int i = blockIdx.x * 1024 + threadIdx.x;
    if (i < M_ROWS) row_start[i] += bsum[i >> 10];
    else if (i == M_ROWS) row_start[M_ROWS] = bsum[nb];
}

__global__ void scatter_kernel(const int* __restrict__ rows, const int* __restrict__ cols,
                               const float* __restrict__ vals,
                               const int* __restrict__ row_start, int* __restrict__ fill,
                               int2* __restrict__ edges) {
    int e = blockIdx.x * 256 + threadIdx.x;
    if (e >= E_EDGES) return;
    int r = rows[e];
    int p = atomicAdd(&fill[r], 1);
    edges[row_start[r] + p] = make_int2(cols[e], __float_as_int(vals[e]));
}

// ---------------- T0 = tile(x), fp32 -> bf16 ----------------

__global__ void tile_kernel(const float* __restrict__ x, __hip_bfloat16* __restrict__ T0) {
    int idx = blockIdx.x * 256 + threadIdx.x;       // covers N_NODES*CH
    T0[(size_t)blockIdx.y * (N_NODES * CH) + idx] = __float2bfloat16(x[idx]);
}

// ---------------- W transpose+convert: Wt[k][n][kk] = W[k][kk][n] ----------------

__global__ void wconv_kernel(const float* __restrict__ W, __hip_bfloat16* __restrict__ Wt) {
    int idx = blockIdx.x * 256 + threadIdx.x;       // 8*512*64 = 262144
    int kk = idx & 511;
    int n  = (idx >> 9) & 63;
    int k  = idx >> 15;
    Wt[((size_t)(k * 64 + n) << 9) + kk] =
        __float2bfloat16(W[(size_t)k * WK_STRIDE + kk * 64 + n]);
}

// ---------------- SpMM: Tout = bf16(alpha * (L @ Tin) + beta * Tsub) ----------------
// one wave per row; lane = channel (bf16, 128B/row gathers)

__global__ __launch_bounds__(256) void spmm_kernel(
        const int* __restrict__ row_start, const int2* __restrict__ edges,
        const __hip_bfloat16* __restrict__ Tin, const __hip_bfloat16* __restrict__ Tsub,
        __hip_bfloat16* __restrict__ Tout, float alpha, float beta) {
    int r = (blockIdx.x * 256 + threadIdx.x) >> 6;
    int lane = threadIdx.x & 63;
    if (r >= M_ROWS) return;
    int s = row_start[r];
    int e = row_start[r + 1];
    float acc = 0.f;
    int j = s;
    // unroll-by-4: four independent gathers in flight
    for (; j + 3 < e; j += 4) {
        int2 e0 = edges[j];
        int2 e1 = edges[j + 1];
        int2 e2 = edges[j + 2];
        int2 e3 = edges[j + 3];
        float t0 = __bfloat162float(Tin[(size_t)e0.x * CH + lane]);
        float t1 = __bfloat162float(Tin[(size_t)e1.x * CH + lane]);
        float t2 = __bfloat162float(Tin[(size_t)e2.x * CH + lane]);
        float t3 = __bfloat162float(Tin[(size_t)e3.x * CH + lane]);
        acc = fmaf(__int_as_float(e0.y), t0, acc);
        acc = fmaf(__int_as_float(e1.y), t1, acc);
        acc = fmaf(__int_as_float(e2.y), t2, acc);
        acc = fmaf(__int_as_float(e3.y), t3, acc);
    }
    for (; j < e; ++j) {
        int2 e0 = edges[j];
        acc = fmaf(__int_as_float(e0.y), __bfloat162float(Tin[(size_t)e0.x * CH + lane]), acc);
    }
    size_t oi = (size_t)r * CH + lane;
    float sub = __bfloat162float(Tsub[oi]);
    Tout[oi] = __float2bfloat16(alpha * acc + beta * sub);
}

// ---------------- GEMM via MFMA: out (+)= feat(T) @ Wk (+ bias) ----------------
// one wave = 16 nodes x 64 outs, K=512 in 16 steps of 32. No LDS:
// A-frags read from bf16 T rows (16B contiguous), B-frags from Wt rows (L1/L2-hot).
// A layout: m=lane&15, k=(lane>>4)*8+j.  B layout: n=lane&15, k=(lane>>4)*8+j.
// C/D layout: col=lane&15, row=(lane>>4)*4+reg  [m89-verified].

template <int ACC>
__global__ __launch_bounds__(256) void gemm_mfma_kernel(
        const __hip_bfloat16* __restrict__ T,    // [NANG*N_NODES, 64] bf16
        const __hip_bfloat16* __restrict__ Wt,   // [64][512] bf16 (this k, transposed)
        const float* __restrict__ bias,
        float* __restrict__ out) {               // [N_NODES, 64] fp32
    int wave = (blockIdx.x * 256 + threadIdx.x) >> 6;
    int l = threadIdx.x & 63;
    int m0 = wave * 16;
    if (m0 >= N_NODES) return;
    int lm = l & 15;
    int lq = l >> 4;

    const short* Tp = (const short*)T;
    const short* Wp = (const short*)Wt;

    f32x4 acc[4];
#pragma unroll
    for (int t = 0; t < 4; ++t) acc[t] = (f32x4){0.f, 0.f, 0.f, 0.f};

#pragma unroll
    for (int ks = 0; ks < 16; ++ks) {
        int a  = ks >> 1;
        int c0 = (ks & 1) * 32;
        short8 af = *(const short8*)(Tp + ((size_t)(a * N_NODES + m0 + lm)) * CH + c0 + lq * 8);
#pragma unroll
        for (int t = 0; t < 4; ++t) {
            short8 bfrag = *(const short8*)(Wp + ((size_t)(t * 16 + lm)) * 512 + ks * 32 + lq * 8);
            acc[t] = __builtin_amdgcn_mfma_f32_16x16x32_bf16(af, bfrag, acc[t], 0, 0, 0);
        }
    }

#pragma unroll
    for (int t = 0; t < 4; ++t) {
        int col = t * 16 + lm;
#pragma unroll
        for (int rI = 0; rI < 4; ++rI) {
            int row = m0 + lq * 4 + rI;
            size_t oi = (size_t)row * CH + col;
            if (ACC) out[oi] += acc[t][rI];
            else     out[oi] = acc[t][rI] + bias[col];
        }
    }
}

// ---------------- launch ----------------

extern "C" void kernel_launch(void* const* d_in, const int* in_sizes, int n_in,
                              void* d_out, int out_size, void* d_ws, size_t ws_size,
                              hipStream_t stream) {
    (void)in_sizes; (void)n_in; (void)out_size; (void)ws_size;
    const float* x       = (const float*)d_in[0];
    const float* ls_vals = (const float*)d_in[1];
    const float* weight  = (const float*)d_in[2];
    const float* bias    = (const float*)d_in[3];
    const int*   ls_rows = (const int*)d_in[4];
    const int*   ls_cols = (const int*)d_in[5];
    float* out = (float*)d_out;

    char* ws = (char*)d_ws;
    size_t off = 0;
    auto alloc = [&](size_t bytes) -> void* {
        void* p = ws + off;
        off += (bytes + 255) & ~(size_t)255;
        return p;
    };
    int*  row_start = (int*)alloc((M_ROWS + 1) * sizeof(int));
    int*  fill      = (int*)alloc(M_ROWS * sizeof(int));       // doubles as counts
    int*  bsum      = (int*)alloc(1024 * sizeof(int));
    int2* edges     = (int2*)alloc((size_t)E_EDGES * sizeof(int2));
    __hip_bfloat16* Wt = (__hip_bfloat16*)alloc((size_t)K_CHEB * 64 * 512 * sizeof(__hip_bfloat16));
    __hip_bfloat16* T0 = (__hip_bfloat16*)alloc((size_t)M_ROWS * CH * sizeof(__hip_bfloat16));
    __hip_bfloat16* T1 = (__hip_bfloat16*)alloc((size_t)M_ROWS * CH * sizeof(__hip_bfloat16));
    __hip_bfloat16* T2 = (__hip_bfloat16*)alloc((size_t)M_ROWS * CH * sizeof(__hip_bfloat16));

    const int nb = (M_ROWS + 1023) / 1024;   // 157
    const int gemm_blocks = (N_NODES / 16 + 3) / 4;   // 313

    // CSR build
    hipMemsetAsync(fill, 0, M_ROWS * sizeof(int), stream);
    hist_kernel<<<(E_EDGES + 255) / 256, 256, 0, stream>>>(ls_rows, fill);
    scan1_kernel<<<nb, 1024, 0, stream>>>(fill, row_start, bsum);
    scan2_kernel<<<1, 256, 0, stream>>>(bsum, nb);
    scan3_kernel<<<nb + 1, 1024, 0, stream>>>(row_start, bsum, nb);
    hipMemsetAsync(fill, 0, M_ROWS * sizeof(int), stream);
    scatter_kernel<<<(E_EDGES + 255) / 256, 256, 0, stream>>>(
        ls_rows, ls_cols, ls_vals, row_start, fill, edges);

    // W -> bf16 transposed; Tx0 = tile(x)
    wconv_kernel<<<(K_CHEB * 512 * 64) / 256, 256, 0, stream>>>(weight, Wt);
    tile_kernel<<<dim3(N_NODES * CH / 256, NANG), 256, 0, stream>>>(x, T0);

    // out = feat(Tx0) @ W0 + bias
    gemm_mfma_kernel<0><<<gemm_blocks, 256, 0, stream>>>(T0, Wt, bias, out);

    // Tx1 = L @ Tx0 ; out += feat(Tx1) @ W1
    spmm_kernel<<<M_ROWS / 4, 256, 0, stream>>>(row_start, edges, T0, T0, T1, 1.f, 0.f);
    gemm_mfma_kernel<1><<<gemm_blocks, 256, 0, stream>>>(T1, Wt + (size_t)1 * 64 * 512, bias, out);

    // Chebyshev: Tx2 = 2 L Tx1 - Tx0
    __hip_bfloat16* Tp = T0;
    __hip_bfloat16* Tc = T1;
    __hip_bfloat16* Tn = T2;
    for (int k = 2; k < K_CHEB; ++k) {
        spmm_kernel<<<M_ROWS / 4, 256, 0, stream>>>(row_start, edges, Tc, Tp, Tn, 2.f, -1.f);
        gemm_mfma_kernel<1><<<gemm_blocks, 256, 0, stream>>>(Tn, Wt + (size_t)k * 64 * 512, bias, out);
        __hip_bfloat16* t = Tp; Tp = Tc; Tc = Tn; Tn = t;
    }
}